// Round 9
// baseline (40.103 us; speedup 1.0000x reference)
//
#include <hip/hip_runtime.h>

#define BB 8
#define NN 4096
#define THREADS 256
#define NSPLIT 64
#define CHUNK (NN / NSPLIT)     // 64 DB points per block = 32 packed pairs
#define NPAIR (CHUNK / 2)       // 32
#define QPT 16                  // queries per thread -> 256*16 = 4096 = all queries of one (dir,b)
#define NQ (BB * NN)            // 32768 queries per direction
#define NQ_TOTAL (2 * NQ)       // 65536

typedef float v2f __attribute__((ext_vector_type(2)));

// t(2 pairs) = W2 + (-q).P2 via 3 packed fma. SEL picks which query (lo/hi word
// of the q-pair registers) is broadcast to both halves via op_sel.
template <int SEL>
__device__ __forceinline__ v2f pk3(v2f X2, v2f Y2, v2f Z2, v2f W2,
                                   v2f qx, v2f qy, v2f qz) {
    v2f t;
    if constexpr (SEL == 0) {
        asm("v_pk_fma_f32 %0, %1, %2, %3 op_sel:[0,0,0] op_sel_hi:[1,0,1]"
            : "=v"(t) : "v"(Z2), "v"(qz), "v"(W2));
        asm("v_pk_fma_f32 %0, %1, %2, %0 op_sel:[0,0,0] op_sel_hi:[1,0,1]"
            : "+v"(t) : "v"(Y2), "v"(qy));
        asm("v_pk_fma_f32 %0, %1, %2, %0 op_sel:[0,0,0] op_sel_hi:[1,0,1]"
            : "+v"(t) : "v"(X2), "v"(qx));
    } else {
        asm("v_pk_fma_f32 %0, %1, %2, %3 op_sel:[0,1,0] op_sel_hi:[1,1,1]"
            : "=v"(t) : "v"(Z2), "v"(qz), "v"(W2));
        asm("v_pk_fma_f32 %0, %1, %2, %0 op_sel:[0,1,0] op_sel_hi:[1,1,1]"
            : "+v"(t) : "v"(Y2), "v"(qy));
        asm("v_pk_fma_f32 %0, %1, %2, %0 op_sel:[0,1,0] op_sel_hi:[1,1,1]"
            : "+v"(t) : "v"(X2), "v"(qx));
    }
    return t;
}

// bid = dir*512 + b*64 + c ; dir0: db=a1,q=a2 (dist1), dir1: db=a2,q=a1
__global__ __launch_bounds__(THREADS) void chamfer_min_kernel(
    const float* __restrict__ a1, const float* __restrict__ a2,
    float* __restrict__ minpart)
{
    // pair-packed DB: sdb4[2p] = {x0,x1,y0,y1}, sdb4[2p+1] = {z0,z1,w0,w1}
    __shared__ float4 sdb4[2 * NPAIR];

    const int tid = threadIdx.x;
    const int bid = blockIdx.x;
    const int c   = bid & (NSPLIT - 1);
    const int b   = (bid >> 6) & 7;
    const int dir = bid >> 9;

    const float* dbg = (dir == 0 ? a1 : a2) + (size_t)b * NN * 3;
    const float* qg  = (dir == 0 ? a2 : a1) + (size_t)b * NN * 3;

    // stage: thread p < NPAIR packs points (2p, 2p+1) of this chunk
    if (tid < NPAIR) {
        const float2* s2 = reinterpret_cast<const float2*>(dbg + (size_t)c * CHUNK * 3);
        const float2 u = s2[3 * tid + 0];   // x0 y0
        const float2 v = s2[3 * tid + 1];   // z0 x1
        const float2 w = s2[3 * tid + 2];   // y1 z1
        const float w0 = 0.5f * fmaf(u.x, u.x, fmaf(u.y, u.y, v.x * v.x));
        const float w1 = 0.5f * fmaf(v.y, v.y, fmaf(w.x, w.x, w.y * w.y));
        sdb4[2 * tid]     = make_float4(u.x, v.y, u.y, w.x);  // x0 x1 y0 y1
        sdb4[2 * tid + 1] = make_float4(v.x, w.y, w0, w1);    // z0 z1 w0 w1
    }

    // 16 consecutive queries per thread, packed 2-per-register-pair, negated
    v2f qc[3][QPT / 2];
    {
        const float4* q4 = reinterpret_cast<const float4*>(qg + (size_t)tid * QPT * 3);
        float f[48];
        #pragma unroll
        for (int v = 0; v < 12; ++v) {
            const float4 w = q4[v];
            f[4 * v + 0] = w.x; f[4 * v + 1] = w.y;
            f[4 * v + 2] = w.z; f[4 * v + 3] = w.w;
        }
        #pragma unroll
        for (int k2 = 0; k2 < QPT / 2; ++k2) {
            qc[0][k2] = (v2f){-f[6 * k2 + 0], -f[6 * k2 + 3]};
            qc[1][k2] = (v2f){-f[6 * k2 + 1], -f[6 * k2 + 4]};
            qc[2][k2] = (v2f){-f[6 * k2 + 2], -f[6 * k2 + 5]};
        }
    }

    __syncthreads();

    float m[QPT];
    #pragma unroll
    for (int k = 0; k < QPT; ++k) m[k] = 3.4e38f;

    // per pair (2 points) x 16 queries: 24 pk_fma + 8... (per query: 3 pk + 1 min3)
    #pragma unroll 2
    for (int ip = 0; ip < NPAIR; ++ip) {
        const float4 A  = sdb4[2 * ip];
        const float4 Bv = sdb4[2 * ip + 1];
        const v2f X2 = (v2f){A.x,  A.y};
        const v2f Y2 = (v2f){A.z,  A.w};
        const v2f Z2 = (v2f){Bv.x, Bv.y};
        const v2f W2 = (v2f){Bv.z, Bv.w};
        #pragma unroll
        for (int k2 = 0; k2 < QPT / 2; ++k2) {
            const v2f t0 = pk3<0>(X2, Y2, Z2, W2, qc[0][k2], qc[1][k2], qc[2][k2]);
            m[2 * k2]     = fminf(fminf(t0[0], t0[1]), m[2 * k2]);
            const v2f t1 = pk3<1>(X2, Y2, Z2, W2, qc[0][k2], qc[1][k2], qc[2][k2]);
            m[2 * k2 + 1] = fminf(fminf(t1[0], t1[1]), m[2 * k2 + 1]);
        }
    }

    const size_t qglob = (size_t)dir * NQ + (size_t)b * NN + (size_t)tid * QPT;
    float4* dst = reinterpret_cast<float4*>(minpart + (size_t)c * NQ_TOTAL + qglob);
    #pragma unroll
    for (int v = 0; v < 4; ++v)
        dst[v] = make_float4(m[4 * v], m[4 * v + 1], m[4 * v + 2], m[4 * v + 3]);
}

// combine the NSPLIT partial mins per query, add ||q||^2, block-sum
__global__ __launch_bounds__(THREADS) void decode_sum_kernel(
    const float* __restrict__ a1, const float* __restrict__ a2,
    const float* __restrict__ minpart, float* __restrict__ partials)
{
    __shared__ float red[THREADS];
    const int tid = threadIdx.x;
    const int bid = blockIdx.x;
    const int gq  = bid * THREADS + tid;
    const int dir = gq >> 15;
    const int b   = (gq >> 12) & 7;
    const int q   = gq & (NN - 1);

    float mn = 3.4e38f;
    #pragma unroll
    for (int cc = 0; cc < NSPLIT; ++cc)
        mn = fminf(mn, minpart[(size_t)cc * NQ_TOTAL + gq]);

    const float* qp = (dir == 0 ? a2 : a1) + ((size_t)b * NN + q) * 3;
    const float qx = qp[0], qy = qp[1], qz = qp[2];
    const float qn = fmaf(qx, qx, fmaf(qy, qy, qz * qz));
    const float d  = fmaf(2.0f, mn, qn);   // ||p-q||^2 = 2*t' + ||q||^2

    red[tid] = d;
    __syncthreads();
    #pragma unroll
    for (int s = THREADS / 2; s > 0; s >>= 1) {
        if (tid < s) red[tid] += red[tid + s];
        __syncthreads();
    }
    if (tid == 0) partials[bid] = red[0];
}

__global__ __launch_bounds__(256) void finalize_kernel(
    const float* __restrict__ partials, float* __restrict__ out)
{
    __shared__ float red[256];
    const int t = threadIdx.x;
    red[t] = partials[t];
    __syncthreads();
    #pragma unroll
    for (int s = 64; s > 0; s >>= 1) {
        if ((t & 127) < s) red[t] += red[t + s];
        __syncthreads();
    }
    if (t == 0) {
        const float inv = 1.0f / (float)(BB * NN);
        const float d1 = red[0]   * inv;   // dir0
        const float d2 = red[128] * inv;   // dir1
        out[0] = d1 + d2;
        out[1] = d1;
        out[2] = d2;
    }
}

extern "C" void kernel_launch(void* const* d_in, const int* in_sizes, int n_in,
                              void* d_out, int out_size, void* d_ws, size_t ws_size,
                              hipStream_t stream)
{
    const float* a1 = (const float*)d_in[0];
    const float* a2 = (const float*)d_in[1];
    float* out = (float*)d_out;

    float* minpart  = (float*)d_ws;   // 64*65536*4 = 16 MB
    float* partials = (float*)((char*)d_ws + (size_t)NSPLIT * NQ_TOTAL * sizeof(float));

    hipLaunchKernelGGL(chamfer_min_kernel, dim3(2 * BB * NSPLIT), dim3(THREADS), 0, stream,
                       a1, a2, minpart);
    hipLaunchKernelGGL(decode_sum_kernel, dim3(NQ_TOTAL / THREADS), dim3(THREADS), 0, stream,
                       a1, a2, minpart, partials);
    hipLaunchKernelGGL(finalize_kernel, dim3(1), dim3(256), 0, stream,
                       partials, out);
}

// Round 10
// 33.186 us; speedup vs baseline: 1.2084x; 1.2084x over previous
//
#include <hip/hip_runtime.h>

#define BB 8
#define NN 4096
#define THREADS 256
#define NSPLIT 16
#define CHUNK (NN / NSPLIT)     // 256 DB points per block
#define NPAIR (CHUNK / 2)       // 128 packed pairs
#define QPT 8                   // queries per thread
#define QPB (THREADS * QPT)     // 2048 queries per block
#define NQ (BB * NN)            // 32768 queries per direction
#define NQ_TOTAL (2 * NQ)       // 65536

typedef float v2f __attribute__((ext_vector_type(2)));

// t'(2 points) = W2 - q.P2 via 3 packed fma; SEL broadcasts lo/hi query of the
// q-pair registers to both halves via op_sel. Verified exact in R9 (absmax 0.0).
template <int SEL>
__device__ __forceinline__ v2f pk3(v2f X2, v2f Y2, v2f Z2, v2f W2,
                                   v2f qx, v2f qy, v2f qz) {
    v2f t;
    if constexpr (SEL == 0) {
        asm("v_pk_fma_f32 %0, %1, %2, %3 op_sel:[0,0,0] op_sel_hi:[1,0,1]"
            : "=v"(t) : "v"(Z2), "v"(qz), "v"(W2));
        asm("v_pk_fma_f32 %0, %1, %2, %0 op_sel:[0,0,0] op_sel_hi:[1,0,1]"
            : "+v"(t) : "v"(Y2), "v"(qy));
        asm("v_pk_fma_f32 %0, %1, %2, %0 op_sel:[0,0,0] op_sel_hi:[1,0,1]"
            : "+v"(t) : "v"(X2), "v"(qx));
    } else {
        asm("v_pk_fma_f32 %0, %1, %2, %3 op_sel:[0,1,0] op_sel_hi:[1,1,1]"
            : "=v"(t) : "v"(Z2), "v"(qz), "v"(W2));
        asm("v_pk_fma_f32 %0, %1, %2, %0 op_sel:[0,1,0] op_sel_hi:[1,1,1]"
            : "+v"(t) : "v"(Y2), "v"(qy));
        asm("v_pk_fma_f32 %0, %1, %2, %0 op_sel:[0,1,0] op_sel_hi:[1,1,1]"
            : "+v"(t) : "v"(X2), "v"(qx));
    }
    return t;
}

// bid = dir*256 + b*32 + qb*16 + c ; dir0: db=a1,q=a2 (dist1), dir1: db=a2,q=a1
__global__ __launch_bounds__(THREADS) void chamfer_min_kernel(
    const float* __restrict__ a1, const float* __restrict__ a2,
    float* __restrict__ minpart)
{
    // pair-packed DB: sdb4[2p] = {x0,x1,y0,y1}, sdb4[2p+1] = {z0,z1,w0,w1}
    __shared__ float4 sdb4[2 * NPAIR];

    const int tid = threadIdx.x;
    const int bid = blockIdx.x;
    const int c   = bid & (NSPLIT - 1);
    const int qb  = (bid >> 4) & 1;
    const int b   = (bid >> 5) & 7;
    const int dir = bid >> 8;

    const float* dbg = (dir == 0 ? a1 : a2) + (size_t)b * NN * 3;
    const float* qg  = (dir == 0 ? a2 : a1) + (size_t)b * NN * 3;

    // stage: thread p < NPAIR packs points (2p, 2p+1) of this chunk
    if (tid < NPAIR) {
        const float2* s2 = reinterpret_cast<const float2*>(dbg + (size_t)c * CHUNK * 3);
        const float2 u = s2[3 * tid + 0];   // x0 y0
        const float2 v = s2[3 * tid + 1];   // z0 x1
        const float2 w = s2[3 * tid + 2];   // y1 z1
        const float w0 = 0.5f * fmaf(u.x, u.x, fmaf(u.y, u.y, v.x * v.x));
        const float w1 = 0.5f * fmaf(v.y, v.y, fmaf(w.x, w.x, w.y * w.y));
        sdb4[2 * tid]     = make_float4(u.x, v.y, u.y, w.x);  // x0 x1 y0 y1
        sdb4[2 * tid + 1] = make_float4(v.x, w.y, w0, w1);    // z0 z1 w0 w1
    }

    // 8 consecutive queries per thread (24 floats = 6 aligned float4 loads),
    // packed 2-per-register-pair, negated
    v2f qc0[QPT / 2], qc1[QPT / 2], qc2[QPT / 2];
    {
        const float4* q4 = reinterpret_cast<const float4*>(
            qg + (size_t)(qb * QPB + tid * QPT) * 3);
        const float4 v0 = q4[0], v1 = q4[1], v2 = q4[2];
        const float4 v3 = q4[3], v4 = q4[4], v5 = q4[5];
        // query j component c = f[3j+c]
        qc0[0] = (v2f){-v0.x, -v0.w};  qc1[0] = (v2f){-v0.y, -v1.x};  qc2[0] = (v2f){-v0.z, -v1.y};
        qc0[1] = (v2f){-v1.z, -v2.y};  qc1[1] = (v2f){-v1.w, -v2.z};  qc2[1] = (v2f){-v2.x, -v2.w};
        qc0[2] = (v2f){-v3.x, -v3.w};  qc1[2] = (v2f){-v3.y, -v4.x};  qc2[2] = (v2f){-v3.z, -v4.y};
        qc0[3] = (v2f){-v4.z, -v5.y};  qc1[3] = (v2f){-v4.w, -v5.z};  qc2[3] = (v2f){-v5.x, -v5.w};
    }

    __syncthreads();

    float m[QPT];
    #pragma unroll
    for (int k = 0; k < QPT; ++k) m[k] = 3.4e38f;

    // depth-2 register prefetch: compute pairs (ip, ip+1) while (ip+2, ip+3) load
    float4 A0 = sdb4[0], B0 = sdb4[1];
    float4 A1 = sdb4[2], B1 = sdb4[3];
    for (int ip = 0; ip < NPAIR - 2; ip += 2) {
        const float4 nA0 = sdb4[2 * ip + 4];
        const float4 nB0 = sdb4[2 * ip + 5];
        const float4 nA1 = sdb4[2 * ip + 6];
        const float4 nB1 = sdb4[2 * ip + 7];
        {
            const v2f X2 = (v2f){A0.x, A0.y}, Y2 = (v2f){A0.z, A0.w};
            const v2f Z2 = (v2f){B0.x, B0.y}, W2 = (v2f){B0.z, B0.w};
            #pragma unroll
            for (int k2 = 0; k2 < QPT / 2; ++k2) {
                const v2f t0 = pk3<0>(X2, Y2, Z2, W2, qc0[k2], qc1[k2], qc2[k2]);
                m[2 * k2]     = fminf(fminf(t0[0], t0[1]), m[2 * k2]);
                const v2f t1 = pk3<1>(X2, Y2, Z2, W2, qc0[k2], qc1[k2], qc2[k2]);
                m[2 * k2 + 1] = fminf(fminf(t1[0], t1[1]), m[2 * k2 + 1]);
            }
        }
        {
            const v2f X2 = (v2f){A1.x, A1.y}, Y2 = (v2f){A1.z, A1.w};
            const v2f Z2 = (v2f){B1.x, B1.y}, W2 = (v2f){B1.z, B1.w};
            #pragma unroll
            for (int k2 = 0; k2 < QPT / 2; ++k2) {
                const v2f t0 = pk3<0>(X2, Y2, Z2, W2, qc0[k2], qc1[k2], qc2[k2]);
                m[2 * k2]     = fminf(fminf(t0[0], t0[1]), m[2 * k2]);
                const v2f t1 = pk3<1>(X2, Y2, Z2, W2, qc0[k2], qc1[k2], qc2[k2]);
                m[2 * k2 + 1] = fminf(fminf(t1[0], t1[1]), m[2 * k2 + 1]);
            }
        }
        A0 = nA0; B0 = nB0; A1 = nA1; B1 = nB1;
    }
    // tail: last two pairs
    #pragma unroll
    for (int rep = 0; rep < 2; ++rep) {
        const float4 A = rep ? A1 : A0;
        const float4 Bv = rep ? B1 : B0;
        const v2f X2 = (v2f){A.x, A.y}, Y2 = (v2f){A.z, A.w};
        const v2f Z2 = (v2f){Bv.x, Bv.y}, W2 = (v2f){Bv.z, Bv.w};
        #pragma unroll
        for (int k2 = 0; k2 < QPT / 2; ++k2) {
            const v2f t0 = pk3<0>(X2, Y2, Z2, W2, qc0[k2], qc1[k2], qc2[k2]);
            m[2 * k2]     = fminf(fminf(t0[0], t0[1]), m[2 * k2]);
            const v2f t1 = pk3<1>(X2, Y2, Z2, W2, qc0[k2], qc1[k2], qc2[k2]);
            m[2 * k2 + 1] = fminf(fminf(t1[0], t1[1]), m[2 * k2 + 1]);
        }
    }

    float4 o0, o1;
    o0.x = m[0]; o0.y = m[1]; o0.z = m[2]; o0.w = m[3];
    o1.x = m[4]; o1.y = m[5]; o1.z = m[6]; o1.w = m[7];

    const size_t qglob = (size_t)dir * NQ + (size_t)b * NN + (size_t)(qb * QPB + tid * QPT);
    float4* dst = reinterpret_cast<float4*>(minpart + (size_t)c * NQ_TOTAL + qglob);
    dst[0] = o0;
    dst[1] = o1;
}

// combine the NSPLIT partial mins per query, add ||q||^2, block-sum
__global__ __launch_bounds__(THREADS) void decode_sum_kernel(
    const float* __restrict__ a1, const float* __restrict__ a2,
    const float* __restrict__ minpart, float* __restrict__ partials)
{
    __shared__ float red[THREADS];
    const int tid = threadIdx.x;
    const int bid = blockIdx.x;
    const int gq  = bid * THREADS + tid;
    const int dir = gq >> 15;
    const int b   = (gq >> 12) & 7;
    const int q   = gq & (NN - 1);

    float mn = 3.4e38f;
    #pragma unroll
    for (int cc = 0; cc < NSPLIT; ++cc)
        mn = fminf(mn, minpart[(size_t)cc * NQ_TOTAL + gq]);

    const float* qp = (dir == 0 ? a2 : a1) + ((size_t)b * NN + q) * 3;
    const float qx = qp[0], qy = qp[1], qz = qp[2];
    const float qn = fmaf(qx, qx, fmaf(qy, qy, qz * qz));
    const float d  = fmaf(2.0f, mn, qn);   // ||p-q||^2 = 2*t' + ||q||^2

    red[tid] = d;
    __syncthreads();
    #pragma unroll
    for (int s = THREADS / 2; s > 0; s >>= 1) {
        if (tid < s) red[tid] += red[tid + s];
        __syncthreads();
    }
    if (tid == 0) partials[bid] = red[0];
}

__global__ __launch_bounds__(256) void finalize_kernel(
    const float* __restrict__ partials, float* __restrict__ out)
{
    __shared__ float red[256];
    const int t = threadIdx.x;
    red[t] = partials[t];
    __syncthreads();
    #pragma unroll
    for (int s = 64; s > 0; s >>= 1) {
        if ((t & 127) < s) red[t] += red[t + s];
        __syncthreads();
    }
    if (t == 0) {
        const float inv = 1.0f / (float)(BB * NN);
        const float d1 = red[0]   * inv;   // dir0
        const float d2 = red[128] * inv;   // dir1
        out[0] = d1 + d2;
        out[1] = d1;
        out[2] = d2;
    }
}

extern "C" void kernel_launch(void* const* d_in, const int* in_sizes, int n_in,
                              void* d_out, int out_size, void* d_ws, size_t ws_size,
                              hipStream_t stream)
{
    const float* a1 = (const float*)d_in[0];
    const float* a2 = (const float*)d_in[1];
    float* out = (float*)d_out;

    float* minpart  = (float*)d_ws;   // 16*65536*4 = 4 MB
    float* partials = (float*)((char*)d_ws + (size_t)NSPLIT * NQ_TOTAL * sizeof(float));

    hipLaunchKernelGGL(chamfer_min_kernel, dim3(2 * BB * 2 * NSPLIT), dim3(THREADS), 0, stream,
                       a1, a2, minpart);
    hipLaunchKernelGGL(decode_sum_kernel, dim3(NQ_TOTAL / THREADS), dim3(THREADS), 0, stream,
                       a1, a2, minpart, partials);
    hipLaunchKernelGGL(finalize_kernel, dim3(1), dim3(256), 0, stream,
                       partials, out);
}